// Round 1
// baseline (1016.791 us; speedup 1.0000x reference)
//
#include <hip/hip_runtime.h>
#include <cstdint>
#include <cstddef>

#define NPTS 4096
#define CDIM 64
#define BDIM 8
#define KNN  20
#define ODIM 64

// ---------------------------------------------------------------------------
// sq[b][n] = sum_c x[b][c][n]^2   (matches reference jnp.sum(x*x, axis=1))
// ---------------------------------------------------------------------------
__global__ __launch_bounds__(256) void sq_kernel(const float* __restrict__ x,
                                                 float* __restrict__ sq) {
  int g = blockIdx.x * 256 + threadIdx.x;            // g = b*N + n
  int b = g >> 12, n = g & (NPTS - 1);
  const float* xb = x + (size_t)b * CDIM * NPTS + n;
  float s = 0.f;
  #pragma unroll
  for (int c = 0; c < CDIM; ++c) { float v = xb[(size_t)c * NPTS]; s += v * v; }
  sq[g] = s;
}

// ---------------------------------------------------------------------------
// dist rows [r0, r0+chunk) of batch b vs all m:
//   dist[r][m] = sq[r0+r] + sq[m] - 2 * sum_c x[c][r0+r]*x[c][m]
// 128x128 tile per block, 8x8 register tile per thread, K=64 single pass.
// ---------------------------------------------------------------------------
__global__ __launch_bounds__(256) void dist_gemm(const float* __restrict__ x,
                                                 const float* __restrict__ sq,
                                                 float* __restrict__ dist,
                                                 int b, int r0) {
  __shared__ float As[CDIM][128];
  __shared__ float Bs[CDIM][128];
  const float* xb = x + (size_t)b * CDIM * NPTS;
  const int tid = threadIdx.x;
  const int mt = blockIdx.x * 128;   // column tile (m)
  const int rt = blockIdx.y * 128;   // row tile (chunk-local)
  {
    const int col = (tid & 31) * 4;
    const int cr  = tid >> 5;        // 0..7
    #pragma unroll
    for (int p = 0; p < 8; ++p) {
      int c = p * 8 + cr;
      *(float4*)&As[c][col] = *(const float4*)(xb + (size_t)c * NPTS + r0 + rt + col);
      *(float4*)&Bs[c][col] = *(const float4*)(xb + (size_t)c * NPTS + mt + col);
    }
  }
  __syncthreads();
  const int tx = tid & 15, ty = tid >> 4;
  float acc[8][8];
  #pragma unroll
  for (int i = 0; i < 8; ++i)
    #pragma unroll
    for (int j = 0; j < 8; ++j) acc[i][j] = 0.f;

  #pragma unroll 4
  for (int c = 0; c < CDIM; ++c) {
    float a8[8], b8[8];
    *(float4*)&a8[0] = *(const float4*)&As[c][ty * 8];
    *(float4*)&a8[4] = *(const float4*)&As[c][ty * 8 + 4];
    *(float4*)&b8[0] = *(const float4*)&Bs[c][tx * 8];
    *(float4*)&b8[4] = *(const float4*)&Bs[c][tx * 8 + 4];
    #pragma unroll
    for (int i = 0; i < 8; ++i)
      #pragma unroll
      for (int j = 0; j < 8; ++j) acc[i][j] += a8[i] * b8[j];
  }

  const float* sqb = sq + b * NPTS;
  #pragma unroll
  for (int i = 0; i < 8; ++i) {
    int r = rt + ty * 8 + i;                         // chunk-local row
    float sr = sqb[r0 + r];
    float out8[8];
    #pragma unroll
    for (int j = 0; j < 8; ++j) {
      int m = mt + tx * 8 + j;
      out8[j] = sr + sqb[m] - 2.0f * acc[i][j];
    }
    float* dr = dist + (size_t)r * NPTS + mt + tx * 8;
    *(float4*)dr       = *(float4*)&out8[0];
    *(float4*)(dr + 4) = *(float4*)&out8[4];
  }
}

// ---------------------------------------------------------------------------
// Top-20 smallest (dist, idx) lexicographic per row. One wave per row.
// Lane holds 64 keys (flipped-float, order-preserving as u32) in registers,
// plus 8 cached group minima packed as ((u64)fkey<<32)|m for tie-break by m
// (matches jax.lax.top_k stability; final set is order-independent anyway).
// ---------------------------------------------------------------------------
__device__ __forceinline__ unsigned flip_f32(float d) {
  unsigned bits = __float_as_uint(d);
  return bits ^ (unsigned)(((int)bits >> 31) | 0x80000000);
}

__global__ __launch_bounds__(256) void topk_kernel(const float* __restrict__ dist,
                                                   int* __restrict__ knn,
                                                   int b, int r0) {
  const int lane = threadIdx.x & 63;
  const int wv   = threadIdx.x >> 6;
  const int r    = blockIdx.x * 4 + wv;              // chunk-local row
  const float* drow = dist + (size_t)r * NPTS;

  unsigned fk[64];
  #pragma unroll
  for (int i = 0; i < 64; ++i) fk[i] = flip_f32(drow[i * 64 + lane]);

  unsigned long long gk[8];
  #pragma unroll
  for (int g = 0; g < 8; ++g) {
    unsigned long long best =
        ((unsigned long long)fk[g * 8] << 32) | (unsigned)(g * 512 + lane);
    #pragma unroll
    for (int i = 1; i < 8; ++i) {
      unsigned long long cand =
          ((unsigned long long)fk[g * 8 + i] << 32) | (unsigned)((g * 8 + i) * 64 + lane);
      if (cand < best) best = cand;
    }
    gk[g] = best;
  }

  int myidx = 0;
  for (int rnd = 0; rnd < KNN; ++rnd) {
    unsigned long long best = gk[0];
    #pragma unroll
    for (int g = 1; g < 8; ++g) best = (gk[g] < best) ? gk[g] : best;
    #pragma unroll
    for (int off = 32; off >= 1; off >>= 1) {
      unsigned long long other = __shfl_xor(best, off, 64);
      if (other < best) best = other;
    }
    unsigned wm = (unsigned)best;                    // winning m (uniform)
    if (lane == rnd) myidx = (int)wm;
    if (lane == (int)(wm & 63u)) {                   // owner lane clears slot
      int slot = (int)(wm >> 6);                     // 0..63
      int g = slot >> 3;
      #pragma unroll
      for (int gg = 0; gg < 8; ++gg) {
        if (gg == g) {
          #pragma unroll
          for (int i = 0; i < 8; ++i)
            if (gg * 8 + i == slot) fk[gg * 8 + i] = 0xFFFFFFFFu;
          unsigned long long bb =
              ((unsigned long long)fk[gg * 8] << 32) | (unsigned)(gg * 512 + lane);
          #pragma unroll
          for (int i = 1; i < 8; ++i) {
            unsigned long long cand =
                ((unsigned long long)fk[gg * 8 + i] << 32) | (unsigned)((gg * 8 + i) * 64 + lane);
            if (cand < bb) bb = cand;
          }
          gk[gg] = bb;
        }
      }
    }
  }
  if (lane < KNN) knn[((size_t)b * NPTS + (r0 + r)) * KNN + lane] = myidx;
}

// ---------------------------------------------------------------------------
// a[b][n][o] = sum_c (W[o][c]-W[o][c+64]) * x[b][c][n]
// cc[b][n][o] = sum_c  W[o][c+64]         * x[b][c][n]
// Block: 64 n's; W staged transposed in LDS.
// ---------------------------------------------------------------------------
__global__ __launch_bounds__(256) void proj_kernel(const float* __restrict__ x,
                                                   const float* __restrict__ w,
                                                   float* __restrict__ a,
                                                   float* __restrict__ cc) {
  __shared__ float wa[CDIM][ODIM];
  __shared__ float wc[CDIM][ODIM];
  const int tid = threadIdx.x;
  #pragma unroll
  for (int p = 0; p < 16; ++p) {
    int idx = p * 256 + tid;                         // 0..4095
    int o = idx & 63, c = idx >> 6;
    float w1 = w[o * 128 + c], w2 = w[o * 128 + 64 + c];
    wa[c][o] = w1 - w2;
    wc[c][o] = w2;
  }
  __syncthreads();
  const int lane = tid & 63, wv = tid >> 6;
  const int gbase = blockIdx.x * 64;
  const int b = gbase >> 12;
  const float* xB = x + (size_t)b * CDIM * NPTS;
  for (int t = 0; t < 16; ++t) {
    int g = gbase + wv * 16 + t;                     // b*N + n
    int n = g & (NPTS - 1);
    float aa = 0.f, ac = 0.f;
    #pragma unroll
    for (int c = 0; c < CDIM; ++c) {
      float xv = xB[(size_t)c * NPTS + n];           // wave-uniform broadcast
      aa += wa[c][lane] * xv;
      ac += wc[c][lane] * xv;
    }
    a [(size_t)g * ODIM + lane] = aa;
    cc[(size_t)g * ODIM + lane] = ac;
  }
}

// ---------------------------------------------------------------------------
// out[b][o][n] = relu(inv[o] * max_k(a[b][n][o] + cc[b][knn[n][k]][o]) + bias[o])
// (valid since inv>0 and relu/affine monotone). LDS transpose for coalesced
// (B,O,N) stores.
// ---------------------------------------------------------------------------
__global__ __launch_bounds__(256) void out_kernel(const float* __restrict__ a,
                                                  const float* __restrict__ cc,
                                                  const int* __restrict__ knn,
                                                  const float* __restrict__ gamma,
                                                  const float* __restrict__ beta,
                                                  const float* __restrict__ mean,
                                                  const float* __restrict__ var,
                                                  float* __restrict__ out) {
  __shared__ float tile[64][65];
  const int tid = threadIdx.x, lane = tid & 63, wv = tid >> 6;
  const int b = blockIdx.y;
  const int n0 = blockIdx.x * 64;
  float inv  = gamma[lane] / sqrtf(var[lane] + 1e-5f);
  float bias = beta[lane] - mean[lane] * inv;
  for (int t = 0; t < 16; ++t) {
    int nl = wv * 16 + t;
    size_t base = (size_t)b * NPTS + (n0 + nl);
    float av = a[base * ODIM + lane];
    const int* kr = knn + base * KNN;
    float m = -INFINITY;
    #pragma unroll
    for (int k = 0; k < KNN; ++k) {
      int j = kr[k];                                 // wave-uniform
      float cv = cc[((size_t)b * NPTS + j) * ODIM + lane];
      m = fmaxf(m, av + cv);
    }
    float v = m * inv + bias;
    tile[nl][lane] = v > 0.f ? v : 0.f;
  }
  __syncthreads();
  for (int t = 0; t < 16; ++t) {
    int o = wv * 16 + t;
    out[((size_t)b * ODIM + o) * NPTS + n0 + lane] = tile[lane][o];
  }
}

// ---------------------------------------------------------------------------
extern "C" void kernel_launch(void* const* d_in, const int* in_sizes, int n_in,
                              void* d_out, int out_size, void* d_ws, size_t ws_size,
                              hipStream_t stream) {
  const float* x     = (const float*)d_in[0];
  const float* w     = (const float*)d_in[1];
  const float* gamma = (const float*)d_in[2];
  const float* beta  = (const float*)d_in[3];
  const float* mean  = (const float*)d_in[4];
  const float* var   = (const float*)d_in[5];
  float* out = (float*)d_out;

  char* wsb = (char*)d_ws;
  size_t off = 0;
  int*   knn = (int*)(wsb + off);  off += (size_t)BDIM * NPTS * KNN * 4;   // 2.62 MB
  float* sq  = (float*)(wsb + off); off += (size_t)BDIM * NPTS * 4;        // 0.13 MB
  float* a   = (float*)(wsb + off); off += (size_t)BDIM * NPTS * ODIM * 4; // 8 MB
  float* cc  = (float*)(wsb + off); off += (size_t)BDIM * NPTS * ODIM * 4; // 8 MB
  float* dist = (float*)(wsb + off);                                       // chunk*16 KB

  // pick the largest dist row-chunk that fits the workspace
  int chunk = 128;
  for (int c2 = 4096; c2 >= 128; c2 >>= 1) {
    if (off + (size_t)c2 * NPTS * 4 <= ws_size) { chunk = c2; break; }
  }

  sq_kernel  <<<BDIM * NPTS / 256, 256, 0, stream>>>(x, sq);
  proj_kernel<<<BDIM * NPTS / 64,  256, 0, stream>>>(x, w, a, cc);

  const int nchunks = NPTS / chunk;
  for (int b = 0; b < BDIM; ++b) {
    for (int ch = 0; ch < nchunks; ++ch) {
      int r0 = ch * chunk;
      dist_gemm  <<<dim3(NPTS / 128, chunk / 128), 256, 0, stream>>>(x, sq, dist, b, r0);
      topk_kernel<<<chunk / 4, 256, 0, stream>>>(dist, knn, b, r0);
    }
  }

  out_kernel<<<dim3(NPTS / 64, BDIM), 256, 0, stream>>>(a, cc, knn, gamma, beta,
                                                        mean, var, out);
}